// Round 6
// baseline (550.127 us; speedup 1.0000x reference)
//
#include <hip/hip_runtime.h>
#include <hip/hip_bf16.h>
#include <math.h>

// Problem constants
#define D_   1024
#define HD_  64
#define NH_  16
#define H_   16
#define KH_  8
#define NT_  128      // tokens per chunk (N)
#define E_   4096
#define RE_  4
#define DE_  4
#define ET_  16
#define S_   2048
#define T_   2048
#define BC_  16
#define EPS_ 1e-5f

typedef short s16x8 __attribute__((ext_vector_type(8)));
typedef float f32x4 __attribute__((ext_vector_type(4)));

__device__ __forceinline__ unsigned short f2bf(float f) {
    union { float f; unsigned int u; } v; v.f = f;
    unsigned int r = (v.u + 0x7fffu + ((v.u >> 16) & 1u)) >> 16;  // RNE
    return (unsigned short)r;
}
__device__ __forceinline__ float bf2f(unsigned short u) {
    union { unsigned int i; float f; } v;
    v.i = ((unsigned int)u) << 16;
    return v.f;
}

// ---------------------------------------------------------------------------
// rmsnorm (fp32 out)
// ---------------------------------------------------------------------------
__global__ __launch_bounds__(256) void rmsnorm_kernel(
    const float* __restrict__ x, const float* __restrict__ w,
    float* __restrict__ out)
{
    int row = blockIdx.x, tid = threadIdx.x;
    __shared__ float sred[4];
    float4 v = ((const float4*)(x + (size_t)row * D_))[tid];
    float ss = v.x*v.x + v.y*v.y + v.z*v.z + v.w*v.w;
#pragma unroll
    for (int off = 32; off > 0; off >>= 1) ss += __shfl_xor(ss, off);
    if ((tid & 63) == 0) sred[tid >> 6] = ss;
    __syncthreads();
    float tot = sred[0] + sred[1] + sred[2] + sred[3];
    float scale = rsqrtf(tot * (1.0f / D_) + EPS_);
    float4 wv = ((const float4*)w)[tid];
    float4 o;
    o.x = v.x * scale * wv.x;
    o.y = v.y * scale * wv.y;
    o.z = v.z * scale * wv.z;
    o.w = v.w * scale * wv.w;
    ((float4*)(out + (size_t)row * D_))[tid] = o;
}

// rmsnorm (bf16 out)
__global__ __launch_bounds__(256) void rmsnorm_bf16_kernel(
    const float* __restrict__ x, const float* __restrict__ w,
    unsigned short* __restrict__ out)
{
    int row = blockIdx.x, tid = threadIdx.x;
    __shared__ float sred[4];
    float4 v = ((const float4*)(x + (size_t)row * D_))[tid];
    float ss = v.x*v.x + v.y*v.y + v.z*v.z + v.w*v.w;
#pragma unroll
    for (int off = 32; off > 0; off >>= 1) ss += __shfl_xor(ss, off);
    if ((tid & 63) == 0) sred[tid >> 6] = ss;
    __syncthreads();
    float tot = sred[0] + sred[1] + sred[2] + sred[3];
    float scale = rsqrtf(tot * (1.0f / D_) + EPS_);
    float4 wv = ((const float4*)w)[tid];
    ushort4 o;
    o.x = f2bf(v.x * scale * wv.x);
    o.y = f2bf(v.y * scale * wv.y);
    o.z = f2bf(v.z * scale * wv.z);
    o.w = f2bf(v.w * scale * wv.w);
    *(ushort4*)(out + (size_t)row * D_ + tid * 4) = o;
}

// ---------------------------------------------------------------------------
// convert + transpose: src [R][Ncols] fp32  ->  dst [Ncols][R] bf16
// ---------------------------------------------------------------------------
__global__ __launch_bounds__(256) void convt_kernel(
    const float* __restrict__ src, unsigned short* __restrict__ dst,
    int R, int Ncols)
{
    __shared__ float tile[32][33];
    int bx = blockIdx.x * 32;   // col block
    int by = blockIdx.y * 32;   // row block
    int tx = threadIdx.x & 31, ty = threadIdx.x >> 5;  // 8 rows per pass
#pragma unroll
    for (int rr = 0; rr < 32; rr += 8)
        tile[ty + rr][tx] = src[(size_t)(by + ty + rr) * Ncols + bx + tx];
    __syncthreads();
#pragma unroll
    for (int rr = 0; rr < 32; rr += 8)
        dst[(size_t)(bx + ty + rr) * R + by + tx] = f2bf(tile[tx][ty + rr]);
}

// ---------------------------------------------------------------------------
// MFMA GEMM: C[M,N] fp32 = A[M,K] bf16 @ Bt[N,K] bf16 (+ res fp32)
// ---------------------------------------------------------------------------
template <int WITH_RES>
__global__ __launch_bounds__(256) void mfma_gemm_kernel(
    const unsigned short* __restrict__ A, const unsigned short* __restrict__ Bt,
    const float* __restrict__ res, float* __restrict__ C,
    int M, int N, int K)
{
    __shared__ short As[128][40];
    __shared__ short Bs[128][40];
    int tid = threadIdx.x;
    int wave = tid >> 6, lane = tid & 63;
    int ml = lane & 15, q = lane >> 4;
    int wr = wave >> 1, wc = wave & 1;
    int bm = blockIdx.y * 128, bn = blockIdx.x * 128;
    int srow = tid >> 2;
    int scol = (tid & 3) * 8;

    f32x4 acc[4][4];
#pragma unroll
    for (int i = 0; i < 4; i++)
#pragma unroll
        for (int j = 0; j < 4; j++) acc[i][j] = (f32x4){0.f, 0.f, 0.f, 0.f};

    for (int k0 = 0; k0 < K; k0 += 32) {
        int4 a0 = *(const int4*)(A + (size_t)(bm + srow) * K + k0 + scol);
        int4 a1 = *(const int4*)(A + (size_t)(bm + srow + 64) * K + k0 + scol);
        int4 b0 = *(const int4*)(Bt + (size_t)(bn + srow) * K + k0 + scol);
        int4 b1 = *(const int4*)(Bt + (size_t)(bn + srow + 64) * K + k0 + scol);
        __syncthreads();
        *(int4*)(&As[srow][scol]) = a0;
        *(int4*)(&As[srow + 64][scol]) = a1;
        *(int4*)(&Bs[srow][scol]) = b0;
        *(int4*)(&Bs[srow + 64][scol]) = b1;
        __syncthreads();

        s16x8 af[4], bf[4];
#pragma unroll
        for (int i = 0; i < 4; i++)
            af[i] = *(const s16x8*)(&As[wr * 64 + i * 16 + ml][q * 8]);
#pragma unroll
        for (int j = 0; j < 4; j++)
            bf[j] = *(const s16x8*)(&Bs[wc * 64 + j * 16 + ml][q * 8]);
#pragma unroll
        for (int i = 0; i < 4; i++)
#pragma unroll
            for (int j = 0; j < 4; j++)
                acc[i][j] = __builtin_amdgcn_mfma_f32_16x16x32_bf16(
                    af[i], bf[j], acc[i][j], 0, 0, 0);
    }

#pragma unroll
    for (int i = 0; i < 4; i++) {
#pragma unroll
        for (int j = 0; j < 4; j++) {
            int col = bn + wc * 64 + j * 16 + ml;
#pragma unroll
            for (int r = 0; r < 4; r++) {
                int row = bm + wr * 64 + i * 16 + q * 4 + r;
                float v = acc[i][j][r];
                if (WITH_RES) v += res[(size_t)row * N + col];
                C[(size_t)row * N + col] = v;
            }
        }
    }
}

// ---------------------------------------------------------------------------
// qkv prep: split qkv into per-head (NH,S,HD) bf16 q/k/v with l2norm + rope.
// ---------------------------------------------------------------------------
__global__ __launch_bounds__(64) void qkv_prep_kernel(
    const float* __restrict__ qkv, unsigned short* __restrict__ qh,
    unsigned short* __restrict__ khb, unsigned short* __restrict__ vhb)
{
    int bid = blockIdx.x;
    int s = bid / NH_, h = bid % NH_;
    int lane = threadIdx.x;

    size_t qoff = (size_t)s * (3 * D_) + h * HD_ + lane;
    float qv = qkv[qoff];
    float kv = qkv[qoff + D_];
    float vv = qkv[qoff + 2 * D_];

    float sq = qv * qv, sk = kv * kv;
#pragma unroll
    for (int off = 32; off > 0; off >>= 1) {
        sq += __shfl_xor(sq, off);
        sk += __shfl_xor(sk, off);
    }
    qv /= fmaxf(sqrtf(sq), EPS_);
    kv /= fmaxf(sqrtf(sk), EPS_);

    int j = lane & 31;
    float sign = (lane < 32) ? 1.0f : -1.0f;
    float inv_freq = exp2f((float)j * (-13.287712379549449f / 32.0f));
    float f = (float)s * inv_freq;
    float sn, cs;
    sincosf(f, &sn, &cs);
    float qo = __shfl_xor(qv, 32);
    float ko = __shfl_xor(kv, 32);
    qv = qv * cs + sign * qo * sn;
    kv = kv * cs + sign * ko * sn;

    size_t o = ((size_t)h * S_ + s) * HD_ + lane;
    qh[o]  = f2bf(qv * 0.125f);   // fold 1/sqrt(64)
    khb[o] = f2bf(kv);
    vhb[o] = f2bf(vv);
}

// ---------------------------------------------------------------------------
// MFMA bf16 flash attention (unchanged from round 4).
// ---------------------------------------------------------------------------
#define NQT_ (S_ / 64)   // 32 q-tiles per head
#define FSTR 72          // shorts per LDS row
__global__ __launch_bounds__(256) void flash_attn_mfma_kernel(
    const unsigned short* __restrict__ qh, const unsigned short* __restrict__ khb,
    const unsigned short* __restrict__ vhb, unsigned short* __restrict__ aob)
{
    __shared__ __align__(16) short Qs[64][FSTR];
    __shared__ __align__(16) short Ks[64][FSTR];
    __shared__ __align__(16) short VsT[64][FSTR];  // [d][token]
    __shared__ __align__(16) short Ps[64][FSTR];
    int h = blockIdx.x >> 4;
    int p = blockIdx.x & 15;
    int tid = threadIdx.x;
    int wq = tid >> 6;
    int lane = tid & 63;
    int ml = lane & 15, quad = lane >> 4;
    int srow = tid >> 2;
    int sc = (tid & 3) * 16;
    const unsigned short* Qb = qh  + (size_t)h * S_ * HD_;
    const unsigned short* Kb = khb + (size_t)h * S_ * HD_;
    const unsigned short* Vb = vhb + (size_t)h * S_ * HD_;

    for (int half = 0; half < 2; half++) {
        int t = half ? (NQT_ - 1 - p) : p;
        int q0 = t * 64;

        {
            int4 v0 = *(const int4*)(Qb + (size_t)(q0 + srow) * HD_ + sc);
            int4 v1 = *(const int4*)(Qb + (size_t)(q0 + srow) * HD_ + sc + 8);
            *(int4*)(&Qs[srow][sc]) = v0;
            *(int4*)(&Qs[srow][sc + 8]) = v1;
        }

        float m[4], l[4];
        f32x4 o[4];
#pragma unroll
        for (int r = 0; r < 4; r++) { m[r] = -INFINITY; l[r] = 0.f; }
#pragma unroll
        for (int nb = 0; nb < 4; nb++) o[nb] = (f32x4){0.f, 0.f, 0.f, 0.f};

        for (int kt = 0; kt <= t; kt++) {
            int k0 = kt * 64;
            __syncthreads();
            {
                int4 k0v = *(const int4*)(Kb + (size_t)(k0 + srow) * HD_ + sc);
                int4 k1v = *(const int4*)(Kb + (size_t)(k0 + srow) * HD_ + sc + 8);
                *(int4*)(&Ks[srow][sc]) = k0v;
                *(int4*)(&Ks[srow][sc + 8]) = k1v;
                union { int4 v[2]; short s[16]; } vv;
                vv.v[0] = *(const int4*)(Vb + (size_t)(k0 + srow) * HD_ + sc);
                vv.v[1] = *(const int4*)(Vb + (size_t)(k0 + srow) * HD_ + sc + 8);
#pragma unroll
                for (int jj = 0; jj < 16; jj++)
                    VsT[sc + jj][srow] = vv.s[jj];
            }
            __syncthreads();

            f32x4 s[4];
#pragma unroll
            for (int nb = 0; nb < 4; nb++) s[nb] = (f32x4){0.f, 0.f, 0.f, 0.f};
            s16x8 aq0 = *(const s16x8*)(&Qs[wq * 16 + ml][quad * 8]);
            s16x8 aq1 = *(const s16x8*)(&Qs[wq * 16 + ml][32 + quad * 8]);
#pragma unroll
            for (int nb = 0; nb < 4; nb++) {
                s16x8 b0 = *(const s16x8*)(&Ks[nb * 16 + ml][quad * 8]);
                s16x8 b1 = *(const s16x8*)(&Ks[nb * 16 + ml][32 + quad * 8]);
                s[nb] = __builtin_amdgcn_mfma_f32_16x16x32_bf16(aq0, b0, s[nb], 0, 0, 0);
                s[nb] = __builtin_amdgcn_mfma_f32_16x16x32_bf16(aq1, b1, s[nb], 0, 0, 0);
            }

            float sv[4][4];
#pragma unroll
            for (int nb = 0; nb < 4; nb++)
#pragma unroll
                for (int r = 0; r < 4; r++) {
                    float v = s[nb][r];
                    if (kt == t && (nb * 16 + ml) > (wq * 16 + quad * 4 + r))
                        v = -1e30f;
                    sv[nb][r] = v;
                }
#pragma unroll
            for (int r = 0; r < 4; r++) {
                float rm = fmaxf(fmaxf(sv[0][r], sv[1][r]),
                                 fmaxf(sv[2][r], sv[3][r]));
#pragma unroll
                for (int off = 1; off < 16; off <<= 1)
                    rm = fmaxf(rm, __shfl_xor(rm, off));
                float mn = fmaxf(m[r], rm);
                float corr = __expf(m[r] - mn);
                m[r] = mn;
                float rs = 0.f;
#pragma unroll
                for (int nb = 0; nb < 4; nb++) {
                    float pe = __expf(sv[nb][r] - mn);
                    sv[nb][r] = pe;
                    rs += pe;
                }
#pragma unroll
                for (int off = 1; off < 16; off <<= 1)
                    rs += __shfl_xor(rs, off);
                l[r] = l[r] * corr + rs;
#pragma unroll
                for (int nb = 0; nb < 4; nb++) o[nb][r] *= corr;
            }

#pragma unroll
            for (int nb = 0; nb < 4; nb++)
#pragma unroll
                for (int r = 0; r < 4; r++)
                    Ps[wq * 16 + quad * 4 + r][nb * 16 + ml] =
                        (short)f2bf(sv[nb][r]);
            __syncthreads();

            s16x8 ap0 = *(const s16x8*)(&Ps[wq * 16 + ml][quad * 8]);
            s16x8 ap1 = *(const s16x8*)(&Ps[wq * 16 + ml][32 + quad * 8]);
#pragma unroll
            for (int nb = 0; nb < 4; nb++) {
                s16x8 b0 = *(const s16x8*)(&VsT[nb * 16 + ml][quad * 8]);
                s16x8 b1 = *(const s16x8*)(&VsT[nb * 16 + ml][32 + quad * 8]);
                o[nb] = __builtin_amdgcn_mfma_f32_16x16x32_bf16(ap0, b0, o[nb], 0, 0, 0);
                o[nb] = __builtin_amdgcn_mfma_f32_16x16x32_bf16(ap1, b1, o[nb], 0, 0, 0);
            }
        }

#pragma unroll
        for (int r = 0; r < 4; r++) {
            float inv = 1.0f / l[r];
            int row = q0 + wq * 16 + quad * 4 + r;
#pragma unroll
            for (int nb = 0; nb < 4; nb++)
                aob[(size_t)row * D_ + h * HD_ + nb * 16 + ml] =
                    f2bf(o[nb][r] * inv);
        }
    }
}

// ---------------------------------------------------------------------------
// gather keys columns into compact bf16 buffer.
// grid = BC*ET*KH blocks; block (pair, kh) loads keys[kh][:, idx[pair]]
// (1024 scalars, stride E) -> kgath[pair][kh][0..1024) bf16.
// Max-occupancy latency hiding for the irreducible line-gather traffic.
// ---------------------------------------------------------------------------
__global__ __launch_bounds__(256) void gather_keys_kernel(
    const float* __restrict__ keys, const int* __restrict__ indices,
    unsigned short* __restrict__ kgath)
{
    int bid = blockIdx.x;
    int pair = bid >> 3, kh = bid & 7;
    int idx = indices[pair];
    int tid = threadIdx.x;
    const float* kp = keys + (size_t)kh * D_ * E_ + idx;
    int d = tid * 4;
    ushort4 o;
    o.x = f2bf(kp[(size_t)(d + 0) * E_]);
    o.y = f2bf(kp[(size_t)(d + 1) * E_]);
    o.z = f2bf(kp[(size_t)(d + 2) * E_]);
    o.w = f2bf(kp[(size_t)(d + 3) * E_]);
    *(ushort4*)(kgath + ((size_t)pair * KH_ + kh) * D_ + d) = o;
}

// ---------------------------------------------------------------------------
// expert scores + combine weights. One block per (chunk c, expert slot e).
// Ks now staged from the compact kgath buffer (coalesced).
// ---------------------------------------------------------------------------
__global__ __launch_bounds__(256) void expert_score_kernel(
    const float* __restrict__ xf, const unsigned short* __restrict__ kgath,
    const float* __restrict__ scores,
    const float* __restrict__ head_probs,
    const float* __restrict__ score_probs,
    const int* __restrict__ indices, float* __restrict__ wbuf)
{
    __shared__ float Ks[KH_][D_];
    __shared__ float Xs[NT_][33];
    __shared__ float Ds[NT_][9];
    __shared__ float sp0[H_], sp1[H_], hp[H_];
    int blk = blockIdx.x;
    int c = blk / ET_, e = blk % ET_;
    int tid = threadIdx.x;
    int idx = indices[c * ET_ + e];
    int r = e / DE_;
    // stage Ks from compact gather (coalesced int4 = 8 bf16 each)
    const unsigned short* kg = kgath + (size_t)blk * KH_ * D_;
#pragma unroll
    for (int it = 0; it < 4; it++) {
        int i = tid + it * 256;                 // i-th group of 8
        union { int4 v; unsigned short s[8]; } u;
        u.v = *(const int4*)(kg + i * 8);
        int kh = (i * 8) >> 10, dd = (i * 8) & 1023;
#pragma unroll
        for (int j = 0; j < 8; j++)
            Ks[kh][dd + j] = bf2f(u.s[j]);
    }
    if (tid < H_) {
        int h = tid;
        sp0[h] = score_probs[((size_t)(0 * RE_ + r) * E_ + idx) * H_ + h];
        sp1[h] = score_probs[((size_t)(1 * RE_ + r) * E_ + idx) * H_ + h];
        hp[h]  = head_probs[((size_t)r * E_ + idx) * H_ + h];
    }
    float acc[4] = {0.f, 0.f, 0.f, 0.f};
    int tl = tid & 127;
    int g = tid >> 7;
    for (int d0 = 0; d0 < D_; d0 += 32) {
        __syncthreads();
        for (int i = tid; i < NT_ * 32; i += 256) {
            int t = i >> 5, d = i & 31;
            Xs[t][d] = xf[((size_t)(c * NT_ + t)) * D_ + d0 + d];
        }
        __syncthreads();
        for (int d = 0; d < 32; d++) {
            float aval = Xs[tl][d];
#pragma unroll
            for (int j = 0; j < 4; j++)
                acc[j] += aval * Ks[g * 4 + j][d0 + d];
        }
    }
    __syncthreads();
#pragma unroll
    for (int j = 0; j < 4; j++) Ds[tl][g * 4 + j] = acc[j];
    __syncthreads();
    if (tid < NT_) {
        int t = c * NT_ + tid;
        float wsum = 0.f;
#pragma unroll
        for (int h = 0; h < H_; h++) {
            float mval = Ds[tid][h >> 1];
            float sc = scores[((size_t)t * ET_ + e) * H_ + h];
            float z = sp0[h] * mval + sp1[h] * sc;
            float cmb = 1.0f / (1.0f + __expf(-z));
            wsum += cmb * hp[h];
        }
        wbuf[t * ET_ + e] = wsum;
    }
}

// ---------------------------------------------------------------------------
// MoE with rank-1 experts. One block per token.
// ---------------------------------------------------------------------------
__global__ __launch_bounds__(256) void moe_kernel(
    const float* __restrict__ xf, const float* __restrict__ xfi,
    const int* __restrict__ indices, const float* __restrict__ wbuf,
    const float* __restrict__ experts, float* __restrict__ out)
{
    int t = blockIdx.x, tid = threadIdx.x;
    int c = t / NT_;
    __shared__ int sidx[ET_];
    __shared__ float sw[ET_];
    __shared__ float r0[4], r1[4];
    if (tid < ET_) {
        sidx[tid] = indices[c * ET_ + tid];
        sw[tid] = wbuf[t * ET_ + tid];
    }
    float4 xv = ((const float4*)(xf + (size_t)t * D_))[tid];
    float acc[4] = {0.f, 0.f, 0.f, 0.f};
    __syncthreads();
    for (int e = 0; e < ET_; e++) {
        int idx = sidx[e];
        size_t base = (size_t)idx * D_;
        float4 w0 = *(const float4*)(experts + base + tid * 4);
        float4 w1 = *(const float4*)(experts + (size_t)E_ * D_ + base + tid * 4);
        float p0 = xv.x * w0.x + xv.y * w0.y + xv.z * w0.z + xv.w * w0.w;
        float p1 = xv.x * w1.x + xv.y * w1.y + xv.z * w1.z + xv.w * w1.w;
#pragma unroll
        for (int off = 32; off > 0; off >>= 1) {
            p0 += __shfl_xor(p0, off);
            p1 += __shfl_xor(p1, off);
        }
        if ((tid & 63) == 0) { r0[tid >> 6] = p0; r1[tid >> 6] = p1; }
        __syncthreads();
        float h0 = r0[0] + r0[1] + r0[2] + r0[3];
        float h1 = r1[0] + r1[1] + r1[2] + r1[3];
        __syncthreads();
        float act = h0 / (1.0f + __expf(-h0)) * h1 * sw[e];
        float4 w2 = *(const float4*)(experts + (size_t)2 * E_ * D_ + base + tid * 4);
        acc[0] += act * w2.x;
        acc[1] += act * w2.y;
        acc[2] += act * w2.z;
        acc[3] += act * w2.w;
    }
    size_t o = (size_t)t * D_ + tid * 4;
    float4 rv = *(const float4*)(xfi + o);
    float4 ov;
    ov.x = acc[0] + rv.x;
    ov.y = acc[1] + rv.y;
    ov.z = acc[2] + rv.z;
    ov.w = acc[3] + rv.w;
    *(float4*)(out + o) = ov;
}

// ---------------------------------------------------------------------------
extern "C" void kernel_launch(void* const* d_in, const int* in_sizes, int n_in,
                              void* d_out, int out_size, void* d_ws, size_t ws_size,
                              hipStream_t stream)
{
    (void)in_sizes; (void)n_in; (void)out_size; (void)ws_size;
    const float* x_input     = (const float*)d_in[0];
    const int*   indices     = (const int*)d_in[1];
    const float* scores      = (const float*)d_in[2];
    const float* attn_w      = (const float*)d_in[3];
    const float* attn_out_w  = (const float*)d_in[4];
    const float* attn_norm_w = (const float*)d_in[5];
    const float* ffn_norm_w  = (const float*)d_in[6];
    const float* ffn_experts = (const float*)d_in[7];
    const float* keys        = (const float*)d_in[8];
    const float* head_probs  = (const float*)d_in[9];
    const float* score_probs = (const float*)d_in[10];
    float* out = (float*)d_out;

    float* ws = (float*)d_ws;
    const size_t MF = 1024 * 1024;
    // Region map (floats), peak 12M floats = 48 MB:
    // A [0,6M): qkv (gemm1 out); after qkv_prep reused as:
    //    aob [0,1M) bf16 | xfi [1M,3M) | xf [3M,5M) | wbuf [5M,..) | woutT [5.5M,6M) bf16
    // B [6M,8M): xnb bf16 (steps 1-3) -> qh bf16 (step 4+)
    // C [8M,10M): wqkvT bf16 (steps 2-3) -> khb bf16 (step 4+)
    // D [10M,12M): vhb bf16 (steps 4-5) -> kgath bf16 [10M,11M) (steps 7.5+)
    float* qkv            = ws;
    unsigned short* aob   = (unsigned short*)ws;
    float* xfi            = ws + 1 * MF;
    float* xf             = ws + 3 * MF;
    float* wbuf           = ws + 5 * MF;
    unsigned short* woutT = (unsigned short*)(ws + 5 * MF + 512 * 1024);
    unsigned short* xnb   = (unsigned short*)(ws + 6 * MF);
    unsigned short* qh    = (unsigned short*)(ws + 6 * MF);
    unsigned short* wqkvT = (unsigned short*)(ws + 8 * MF);
    unsigned short* khb   = (unsigned short*)(ws + 8 * MF);
    unsigned short* vhb   = (unsigned short*)(ws + 10 * MF);
    unsigned short* kgath = (unsigned short*)(ws + 10 * MF);  // after flash

    // 1) rmsnorm -> bf16 A
    rmsnorm_bf16_kernel<<<T_, 256, 0, stream>>>(x_input, attn_norm_w, xnb);

    // 2) attn_w (1024 x 3072) -> wqkvT [3072][1024] bf16
    {
        dim3 g(3 * D_ / 32, D_ / 32);
        convt_kernel<<<g, 256, 0, stream>>>(attn_w, wqkvT, D_, 3 * D_);
    }

    // 3) qkv = xnb @ attn_w   (MFMA)
    {
        dim3 g(3 * D_ / 128, T_ / 128);
        mfma_gemm_kernel<0><<<g, 256, 0, stream>>>(xnb, wqkvT, nullptr, qkv,
                                                   T_, 3 * D_, D_);
    }

    // 4) split + l2norm + rope -> bf16 q/k/v
    qkv_prep_kernel<<<T_ * NH_, 64, 0, stream>>>(qkv, qh, khb, vhb);

    // 5) MFMA flash attention -> aob bf16
    flash_attn_mfma_kernel<<<NH_ * 16, 256, 0, stream>>>(qh, khb, vhb, aob);

    // 6) attn_out_w (1024 x 1024) -> woutT [1024][1024] bf16
    {
        dim3 g(D_ / 32, D_ / 32);
        convt_kernel<<<g, 256, 0, stream>>>(attn_out_w, woutT, D_, D_);
    }

    // 7) xfi = aob @ attn_out_w + x_input   (MFMA + residual)
    {
        dim3 g(D_ / 128, T_ / 128);
        mfma_gemm_kernel<1><<<g, 256, 0, stream>>>(aob, woutT, x_input, xfi,
                                                   T_, D_, D_);
    }

    // 7.5) gather keys columns (vhb dead after step 5)
    gather_keys_kernel<<<BC_ * ET_ * KH_, 256, 0, stream>>>(keys, indices, kgath);

    // 8) rmsnorm fp32
    rmsnorm_kernel<<<T_, 256, 0, stream>>>(xfi, ffn_norm_w, xf);

    // 9) expert scores -> combine weights
    expert_score_kernel<<<BC_ * ET_, 256, 0, stream>>>(
        xf, kgath, scores, head_probs, score_probs, indices, wbuf);

    // 10) MoE + final residual
    moe_kernel<<<T_, 256, 0, stream>>>(xf, xfi, indices, wbuf, ffn_experts, out);
}

// Round 7
// 457.487 us; speedup vs baseline: 1.2025x; 1.2025x over previous
//
#include <hip/hip_runtime.h>
#include <hip/hip_bf16.h>
#include <math.h>

// Problem constants
#define D_   1024
#define HD_  64
#define NH_  16
#define H_   16
#define KH_  8
#define NT_  128      // tokens per chunk (N)
#define E_   4096
#define RE_  4
#define DE_  4
#define ET_  16
#define S_   2048
#define T_   2048
#define BC_  16
#define EPS_ 1e-5f

typedef short s16x8 __attribute__((ext_vector_type(8)));
typedef float f32x4 __attribute__((ext_vector_type(4)));

__device__ __forceinline__ unsigned short f2bf(float f) {
    union { float f; unsigned int u; } v; v.f = f;
    unsigned int r = (v.u + 0x7fffu + ((v.u >> 16) & 1u)) >> 16;  // RNE
    return (unsigned short)r;
}
__device__ __forceinline__ float bf2f(unsigned short u) {
    union { unsigned int i; float f; } v;
    v.i = ((unsigned int)u) << 16;
    return v.f;
}

// ---------------------------------------------------------------------------
// rmsnorm (fp32 out)
// ---------------------------------------------------------------------------
__global__ __launch_bounds__(256) void rmsnorm_kernel(
    const float* __restrict__ x, const float* __restrict__ w,
    float* __restrict__ out)
{
    int row = blockIdx.x, tid = threadIdx.x;
    __shared__ float sred[4];
    float4 v = ((const float4*)(x + (size_t)row * D_))[tid];
    float ss = v.x*v.x + v.y*v.y + v.z*v.z + v.w*v.w;
#pragma unroll
    for (int off = 32; off > 0; off >>= 1) ss += __shfl_xor(ss, off);
    if ((tid & 63) == 0) sred[tid >> 6] = ss;
    __syncthreads();
    float tot = sred[0] + sred[1] + sred[2] + sred[3];
    float scale = rsqrtf(tot * (1.0f / D_) + EPS_);
    float4 wv = ((const float4*)w)[tid];
    float4 o;
    o.x = v.x * scale * wv.x;
    o.y = v.y * scale * wv.y;
    o.z = v.z * scale * wv.z;
    o.w = v.w * scale * wv.w;
    ((float4*)(out + (size_t)row * D_))[tid] = o;
}

// rmsnorm (bf16 out)
__global__ __launch_bounds__(256) void rmsnorm_bf16_kernel(
    const float* __restrict__ x, const float* __restrict__ w,
    unsigned short* __restrict__ out)
{
    int row = blockIdx.x, tid = threadIdx.x;
    __shared__ float sred[4];
    float4 v = ((const float4*)(x + (size_t)row * D_))[tid];
    float ss = v.x*v.x + v.y*v.y + v.z*v.z + v.w*v.w;
#pragma unroll
    for (int off = 32; off > 0; off >>= 1) ss += __shfl_xor(ss, off);
    if ((tid & 63) == 0) sred[tid >> 6] = ss;
    __syncthreads();
    float tot = sred[0] + sred[1] + sred[2] + sred[3];
    float scale = rsqrtf(tot * (1.0f / D_) + EPS_);
    float4 wv = ((const float4*)w)[tid];
    ushort4 o;
    o.x = f2bf(v.x * scale * wv.x);
    o.y = f2bf(v.y * scale * wv.y);
    o.z = f2bf(v.z * scale * wv.z);
    o.w = f2bf(v.w * scale * wv.w);
    *(ushort4*)(out + (size_t)row * D_ + tid * 4) = o;
}

// rmsnorm dual: fp32 out + bf16 out
__global__ __launch_bounds__(256) void rmsnorm_dual_kernel(
    const float* __restrict__ x, const float* __restrict__ w,
    float* __restrict__ out, unsigned short* __restrict__ outb)
{
    int row = blockIdx.x, tid = threadIdx.x;
    __shared__ float sred[4];
    float4 v = ((const float4*)(x + (size_t)row * D_))[tid];
    float ss = v.x*v.x + v.y*v.y + v.z*v.z + v.w*v.w;
#pragma unroll
    for (int off = 32; off > 0; off >>= 1) ss += __shfl_xor(ss, off);
    if ((tid & 63) == 0) sred[tid >> 6] = ss;
    __syncthreads();
    float tot = sred[0] + sred[1] + sred[2] + sred[3];
    float scale = rsqrtf(tot * (1.0f / D_) + EPS_);
    float4 wv = ((const float4*)w)[tid];
    float4 o;
    o.x = v.x * scale * wv.x;
    o.y = v.y * scale * wv.y;
    o.z = v.z * scale * wv.z;
    o.w = v.w * scale * wv.w;
    ((float4*)(out + (size_t)row * D_))[tid] = o;
    ushort4 ob;
    ob.x = f2bf(o.x); ob.y = f2bf(o.y); ob.z = f2bf(o.z); ob.w = f2bf(o.w);
    *(ushort4*)(outb + (size_t)row * D_ + tid * 4) = ob;
}

// ---------------------------------------------------------------------------
// convert + transpose: src [R][Ncols] fp32  ->  dst [Ncols][R] bf16
// ---------------------------------------------------------------------------
__global__ __launch_bounds__(256) void convt_kernel(
    const float* __restrict__ src, unsigned short* __restrict__ dst,
    int R, int Ncols)
{
    __shared__ float tile[32][33];
    int bx = blockIdx.x * 32;   // col block
    int by = blockIdx.y * 32;   // row block
    int tx = threadIdx.x & 31, ty = threadIdx.x >> 5;  // 8 rows per pass
#pragma unroll
    for (int rr = 0; rr < 32; rr += 8)
        tile[ty + rr][tx] = src[(size_t)(by + ty + rr) * Ncols + bx + tx];
    __syncthreads();
#pragma unroll
    for (int rr = 0; rr < 32; rr += 8)
        dst[(size_t)(bx + ty + rr) * R + by + tx] = f2bf(tile[tx][ty + rr]);
}

// ---------------------------------------------------------------------------
// MFMA GEMM: C[M,N] fp32 = A[M,K] bf16 @ Bt[N,K] bf16 (+ res fp32)
// ---------------------------------------------------------------------------
template <int WITH_RES>
__global__ __launch_bounds__(256) void mfma_gemm_kernel(
    const unsigned short* __restrict__ A, const unsigned short* __restrict__ Bt,
    const float* __restrict__ res, float* __restrict__ C,
    int M, int N, int K)
{
    __shared__ short As[128][40];
    __shared__ short Bs[128][40];
    int tid = threadIdx.x;
    int wave = tid >> 6, lane = tid & 63;
    int ml = lane & 15, q = lane >> 4;
    int wr = wave >> 1, wc = wave & 1;
    int bm = blockIdx.y * 128, bn = blockIdx.x * 128;
    int srow = tid >> 2;
    int scol = (tid & 3) * 8;

    f32x4 acc[4][4];
#pragma unroll
    for (int i = 0; i < 4; i++)
#pragma unroll
        for (int j = 0; j < 4; j++) acc[i][j] = (f32x4){0.f, 0.f, 0.f, 0.f};

    for (int k0 = 0; k0 < K; k0 += 32) {
        int4 a0 = *(const int4*)(A + (size_t)(bm + srow) * K + k0 + scol);
        int4 a1 = *(const int4*)(A + (size_t)(bm + srow + 64) * K + k0 + scol);
        int4 b0 = *(const int4*)(Bt + (size_t)(bn + srow) * K + k0 + scol);
        int4 b1 = *(const int4*)(Bt + (size_t)(bn + srow + 64) * K + k0 + scol);
        __syncthreads();
        *(int4*)(&As[srow][scol]) = a0;
        *(int4*)(&As[srow + 64][scol]) = a1;
        *(int4*)(&Bs[srow][scol]) = b0;
        *(int4*)(&Bs[srow + 64][scol]) = b1;
        __syncthreads();

        s16x8 af[4], bf[4];
#pragma unroll
        for (int i = 0; i < 4; i++)
            af[i] = *(const s16x8*)(&As[wr * 64 + i * 16 + ml][q * 8]);
#pragma unroll
        for (int j = 0; j < 4; j++)
            bf[j] = *(const s16x8*)(&Bs[wc * 64 + j * 16 + ml][q * 8]);
#pragma unroll
        for (int i = 0; i < 4; i++)
#pragma unroll
            for (int j = 0; j < 4; j++)
                acc[i][j] = __builtin_amdgcn_mfma_f32_16x16x32_bf16(
                    af[i], bf[j], acc[i][j], 0, 0, 0);
    }

#pragma unroll
    for (int i = 0; i < 4; i++) {
#pragma unroll
        for (int j = 0; j < 4; j++) {
            int col = bn + wc * 64 + j * 16 + ml;
#pragma unroll
            for (int r = 0; r < 4; r++) {
                int row = bm + wr * 64 + i * 16 + q * 4 + r;
                float v = acc[i][j][r];
                if (WITH_RES) v += res[(size_t)row * N + col];
                C[(size_t)row * N + col] = v;
            }
        }
    }
}

// ---------------------------------------------------------------------------
// qkv prep: split qkv into per-head (NH,S,HD) bf16 q/k/v with l2norm + rope.
// ---------------------------------------------------------------------------
__global__ __launch_bounds__(64) void qkv_prep_kernel(
    const float* __restrict__ qkv, unsigned short* __restrict__ qh,
    unsigned short* __restrict__ khb, unsigned short* __restrict__ vhb)
{
    int bid = blockIdx.x;
    int s = bid / NH_, h = bid % NH_;
    int lane = threadIdx.x;

    size_t qoff = (size_t)s * (3 * D_) + h * HD_ + lane;
    float qv = qkv[qoff];
    float kv = qkv[qoff + D_];
    float vv = qkv[qoff + 2 * D_];

    float sq = qv * qv, sk = kv * kv;
#pragma unroll
    for (int off = 32; off > 0; off >>= 1) {
        sq += __shfl_xor(sq, off);
        sk += __shfl_xor(sk, off);
    }
    qv /= fmaxf(sqrtf(sq), EPS_);
    kv /= fmaxf(sqrtf(sk), EPS_);

    int j = lane & 31;
    float sign = (lane < 32) ? 1.0f : -1.0f;
    float inv_freq = exp2f((float)j * (-13.287712379549449f / 32.0f));
    float f = (float)s * inv_freq;
    float sn, cs;
    sincosf(f, &sn, &cs);
    float qo = __shfl_xor(qv, 32);
    float ko = __shfl_xor(kv, 32);
    qv = qv * cs + sign * qo * sn;
    kv = kv * cs + sign * ko * sn;

    size_t o = ((size_t)h * S_ + s) * HD_ + lane;
    qh[o]  = f2bf(qv * 0.125f);   // fold 1/sqrt(64)
    khb[o] = f2bf(kv);
    vhb[o] = f2bf(vv);
}

// ---------------------------------------------------------------------------
// MFMA bf16 flash attention (unchanged).
// ---------------------------------------------------------------------------
#define NQT_ (S_ / 64)   // 32 q-tiles per head
#define FSTR 72          // shorts per LDS row
__global__ __launch_bounds__(256) void flash_attn_mfma_kernel(
    const unsigned short* __restrict__ qh, const unsigned short* __restrict__ khb,
    const unsigned short* __restrict__ vhb, unsigned short* __restrict__ aob)
{
    __shared__ __align__(16) short Qs[64][FSTR];
    __shared__ __align__(16) short Ks[64][FSTR];
    __shared__ __align__(16) short VsT[64][FSTR];  // [d][token]
    __shared__ __align__(16) short Ps[64][FSTR];
    int h = blockIdx.x >> 4;
    int p = blockIdx.x & 15;
    int tid = threadIdx.x;
    int wq = tid >> 6;
    int lane = tid & 63;
    int ml = lane & 15, quad = lane >> 4;
    int srow = tid >> 2;
    int sc = (tid & 3) * 16;
    const unsigned short* Qb = qh  + (size_t)h * S_ * HD_;
    const unsigned short* Kb = khb + (size_t)h * S_ * HD_;
    const unsigned short* Vb = vhb + (size_t)h * S_ * HD_;

    for (int half = 0; half < 2; half++) {
        int t = half ? (NQT_ - 1 - p) : p;
        int q0 = t * 64;

        {
            int4 v0 = *(const int4*)(Qb + (size_t)(q0 + srow) * HD_ + sc);
            int4 v1 = *(const int4*)(Qb + (size_t)(q0 + srow) * HD_ + sc + 8);
            *(int4*)(&Qs[srow][sc]) = v0;
            *(int4*)(&Qs[srow][sc + 8]) = v1;
        }

        float m[4], l[4];
        f32x4 o[4];
#pragma unroll
        for (int r = 0; r < 4; r++) { m[r] = -INFINITY; l[r] = 0.f; }
#pragma unroll
        for (int nb = 0; nb < 4; nb++) o[nb] = (f32x4){0.f, 0.f, 0.f, 0.f};

        for (int kt = 0; kt <= t; kt++) {
            int k0 = kt * 64;
            __syncthreads();
            {
                int4 k0v = *(const int4*)(Kb + (size_t)(k0 + srow) * HD_ + sc);
                int4 k1v = *(const int4*)(Kb + (size_t)(k0 + srow) * HD_ + sc + 8);
                *(int4*)(&Ks[srow][sc]) = k0v;
                *(int4*)(&Ks[srow][sc + 8]) = k1v;
                union { int4 v[2]; short s[16]; } vv;
                vv.v[0] = *(const int4*)(Vb + (size_t)(k0 + srow) * HD_ + sc);
                vv.v[1] = *(const int4*)(Vb + (size_t)(k0 + srow) * HD_ + sc + 8);
#pragma unroll
                for (int jj = 0; jj < 16; jj++)
                    VsT[sc + jj][srow] = vv.s[jj];
            }
            __syncthreads();

            f32x4 s[4];
#pragma unroll
            for (int nb = 0; nb < 4; nb++) s[nb] = (f32x4){0.f, 0.f, 0.f, 0.f};
            s16x8 aq0 = *(const s16x8*)(&Qs[wq * 16 + ml][quad * 8]);
            s16x8 aq1 = *(const s16x8*)(&Qs[wq * 16 + ml][32 + quad * 8]);
#pragma unroll
            for (int nb = 0; nb < 4; nb++) {
                s16x8 b0 = *(const s16x8*)(&Ks[nb * 16 + ml][quad * 8]);
                s16x8 b1 = *(const s16x8*)(&Ks[nb * 16 + ml][32 + quad * 8]);
                s[nb] = __builtin_amdgcn_mfma_f32_16x16x32_bf16(aq0, b0, s[nb], 0, 0, 0);
                s[nb] = __builtin_amdgcn_mfma_f32_16x16x32_bf16(aq1, b1, s[nb], 0, 0, 0);
            }

            float sv[4][4];
#pragma unroll
            for (int nb = 0; nb < 4; nb++)
#pragma unroll
                for (int r = 0; r < 4; r++) {
                    float v = s[nb][r];
                    if (kt == t && (nb * 16 + ml) > (wq * 16 + quad * 4 + r))
                        v = -1e30f;
                    sv[nb][r] = v;
                }
#pragma unroll
            for (int r = 0; r < 4; r++) {
                float rm = fmaxf(fmaxf(sv[0][r], sv[1][r]),
                                 fmaxf(sv[2][r], sv[3][r]));
#pragma unroll
                for (int off = 1; off < 16; off <<= 1)
                    rm = fmaxf(rm, __shfl_xor(rm, off));
                float mn = fmaxf(m[r], rm);
                float corr = __expf(m[r] - mn);
                m[r] = mn;
                float rs = 0.f;
#pragma unroll
                for (int nb = 0; nb < 4; nb++) {
                    float pe = __expf(sv[nb][r] - mn);
                    sv[nb][r] = pe;
                    rs += pe;
                }
#pragma unroll
                for (int off = 1; off < 16; off <<= 1)
                    rs += __shfl_xor(rs, off);
                l[r] = l[r] * corr + rs;
#pragma unroll
                for (int nb = 0; nb < 4; nb++) o[nb][r] *= corr;
            }

#pragma unroll
            for (int nb = 0; nb < 4; nb++)
#pragma unroll
                for (int r = 0; r < 4; r++)
                    Ps[wq * 16 + quad * 4 + r][nb * 16 + ml] =
                        (short)f2bf(sv[nb][r]);
            __syncthreads();

            s16x8 ap0 = *(const s16x8*)(&Ps[wq * 16 + ml][quad * 8]);
            s16x8 ap1 = *(const s16x8*)(&Ps[wq * 16 + ml][32 + quad * 8]);
#pragma unroll
            for (int nb = 0; nb < 4; nb++) {
                s16x8 b0 = *(const s16x8*)(&VsT[nb * 16 + ml][quad * 8]);
                s16x8 b1 = *(const s16x8*)(&VsT[nb * 16 + ml][32 + quad * 8]);
                o[nb] = __builtin_amdgcn_mfma_f32_16x16x32_bf16(ap0, b0, o[nb], 0, 0, 0);
                o[nb] = __builtin_amdgcn_mfma_f32_16x16x32_bf16(ap1, b1, o[nb], 0, 0, 0);
            }
        }

#pragma unroll
        for (int r = 0; r < 4; r++) {
            float inv = 1.0f / l[r];
            int row = q0 + wq * 16 + quad * 4 + r;
#pragma unroll
            for (int nb = 0; nb < 4; nb++)
                aob[(size_t)row * D_ + h * HD_ + nb * 16 + ml] =
                    f2bf(o[nb][r] * inv);
        }
    }
}

// ---------------------------------------------------------------------------
// gather keys columns into compact bf16 buffer.
// block (pair, kh) -> kgath[pair][kh][0..1024) bf16
// Per chunk c, row n = e*8+kh at offset (c*128+n)*1024: contiguous Bt layout.
// ---------------------------------------------------------------------------
__global__ __launch_bounds__(256) void gather_keys_kernel(
    const float* __restrict__ keys, const int* __restrict__ indices,
    unsigned short* __restrict__ kgath)
{
    int bid = blockIdx.x;
    int pair = bid >> 3, kh = bid & 7;
    int idx = indices[pair];
    int tid = threadIdx.x;
    const float* kp = keys + (size_t)kh * D_ * E_ + idx;
    int d = tid * 4;
    ushort4 o;
    o.x = f2bf(kp[(size_t)(d + 0) * E_]);
    o.y = f2bf(kp[(size_t)(d + 1) * E_]);
    o.z = f2bf(kp[(size_t)(d + 2) * E_]);
    o.w = f2bf(kp[(size_t)(d + 3) * E_]);
    *(ushort4*)(kgath + ((size_t)pair * KH_ + kh) * D_ + d) = o;
}

// ---------------------------------------------------------------------------
// expert score GEMM (one block per chunk): msbuf[c][128 t][128 n] fp32 =
//   xfb[c*128..][1024] @ kgath[c*128..][1024]^T   (n = e*8+kh)
// ---------------------------------------------------------------------------
__global__ __launch_bounds__(256) void score_gemm_kernel(
    const unsigned short* __restrict__ xfb, const unsigned short* __restrict__ kgath,
    float* __restrict__ msbuf)
{
    __shared__ short As[128][40];
    __shared__ short Bs[128][40];
    int c = blockIdx.x;
    const unsigned short* A  = xfb   + (size_t)c * 128 * D_;
    const unsigned short* Bt = kgath + (size_t)c * 128 * D_;
    int tid = threadIdx.x;
    int wave = tid >> 6, lane = tid & 63;
    int ml = lane & 15, q = lane >> 4;
    int wr = wave >> 1, wc = wave & 1;
    int srow = tid >> 2;
    int scol = (tid & 3) * 8;

    f32x4 acc[4][4];
#pragma unroll
    for (int i = 0; i < 4; i++)
#pragma unroll
        for (int j = 0; j < 4; j++) acc[i][j] = (f32x4){0.f, 0.f, 0.f, 0.f};

    for (int k0 = 0; k0 < D_; k0 += 32) {
        int4 a0 = *(const int4*)(A + (size_t)srow * D_ + k0 + scol);
        int4 a1 = *(const int4*)(A + (size_t)(srow + 64) * D_ + k0 + scol);
        int4 b0 = *(const int4*)(Bt + (size_t)srow * D_ + k0 + scol);
        int4 b1 = *(const int4*)(Bt + (size_t)(srow + 64) * D_ + k0 + scol);
        __syncthreads();
        *(int4*)(&As[srow][scol]) = a0;
        *(int4*)(&As[srow + 64][scol]) = a1;
        *(int4*)(&Bs[srow][scol]) = b0;
        *(int4*)(&Bs[srow + 64][scol]) = b1;
        __syncthreads();

        s16x8 af[4], bf[4];
#pragma unroll
        for (int i = 0; i < 4; i++)
            af[i] = *(const s16x8*)(&As[wr * 64 + i * 16 + ml][q * 8]);
#pragma unroll
        for (int j = 0; j < 4; j++)
            bf[j] = *(const s16x8*)(&Bs[wc * 64 + j * 16 + ml][q * 8]);
#pragma unroll
        for (int i = 0; i < 4; i++)
#pragma unroll
            for (int j = 0; j < 4; j++)
                acc[i][j] = __builtin_amdgcn_mfma_f32_16x16x32_bf16(
                    af[i], bf[j], acc[i][j], 0, 0, 0);
    }

    float* out = msbuf + (size_t)c * 128 * 128;
#pragma unroll
    for (int i = 0; i < 4; i++)
#pragma unroll
        for (int j = 0; j < 4; j++) {
            int col = wc * 64 + j * 16 + ml;
#pragma unroll
            for (int r = 0; r < 4; r++) {
                int row = wr * 64 + i * 16 + q * 4 + r;
                out[(size_t)row * 128 + col] = acc[i][j][r];
            }
        }
}

// ---------------------------------------------------------------------------
// gather sp0/sp1/hp per (chunk, e, h) into coalesced spbuf[c][3][256]
// ---------------------------------------------------------------------------
__global__ __launch_bounds__(256) void gather_sp_kernel(
    const float* __restrict__ score_probs, const float* __restrict__ head_probs,
    const int* __restrict__ indices, float* __restrict__ spbuf)
{
    int c = blockIdx.x, tid = threadIdx.x;
    int e = tid >> 4, h = tid & 15;
    int idx = indices[c * ET_ + e];
    int r = e >> 2;   // e / DE_
    float v0 = score_probs[((size_t)(0 * RE_ + r) * E_ + idx) * H_ + h];
    float v1 = score_probs[((size_t)(1 * RE_ + r) * E_ + idx) * H_ + h];
    float v2 = head_probs[((size_t)r * E_ + idx) * H_ + h];
    float* sp = spbuf + (size_t)c * 3 * 256;
    sp[tid] = v0;
    sp[256 + tid] = v1;
    sp[512 + tid] = v2;
}

// ---------------------------------------------------------------------------
// MoE with rank-1 experts + fused combine-weight computation.
// One block per token; prologue computes sw[e] from msbuf/scores/spbuf.
// ---------------------------------------------------------------------------
__global__ __launch_bounds__(256) void moe_kernel(
    const float* __restrict__ xf, const float* __restrict__ xfi,
    const int* __restrict__ indices, const float* __restrict__ msbuf,
    const float* __restrict__ scores, const float* __restrict__ spbuf,
    const float* __restrict__ experts, float* __restrict__ out)
{
    int t = blockIdx.x, tid = threadIdx.x;
    int c = t / NT_;
    __shared__ int sidx[ET_];
    __shared__ float sw[ET_];
    __shared__ float r0[4], r1[4];
    if (tid < ET_) sidx[tid] = indices[c * ET_ + tid];
    // ---- combine weights: thread = (e = tid>>4, h = tid&15) ----
    {
        int e = tid >> 4, h = tid & 15;
        float ms = msbuf[(size_t)t * 128 + e * 8 + (h >> 1)];
        float sc = scores[(size_t)t * (ET_ * H_) + tid];
        const float* sp = spbuf + (size_t)c * 3 * 256;
        float z = sp[tid] * ms + sp[256 + tid] * sc;
        float term = sp[512 + tid] / (1.0f + __expf(-z));
#pragma unroll
        for (int off = 1; off < 16; off <<= 1)
            term += __shfl_xor(term, off);
        if (h == 0) sw[e] = term;
    }
    float4 xv = ((const float4*)(xf + (size_t)t * D_))[tid];
    float acc[4] = {0.f, 0.f, 0.f, 0.f};
    __syncthreads();
    for (int e = 0; e < ET_; e++) {
        int idx = sidx[e];
        size_t base = (size_t)idx * D_;
        float4 w0 = *(const float4*)(experts + base + tid * 4);
        float4 w1 = *(const float4*)(experts + (size_t)E_ * D_ + base + tid * 4);
        float p0 = xv.x * w0.x + xv.y * w0.y + xv.z * w0.z + xv.w * w0.w;
        float p1 = xv.x * w1.x + xv.y * w1.y + xv.z * w1.z + xv.w * w1.w;
#pragma unroll
        for (int off = 32; off > 0; off >>= 1) {
            p0 += __shfl_xor(p0, off);
            p1 += __shfl_xor(p1, off);
        }
        if ((tid & 63) == 0) { r0[tid >> 6] = p0; r1[tid >> 6] = p1; }
        __syncthreads();
        float h0 = r0[0] + r0[1] + r0[2] + r0[3];
        float h1 = r1[0] + r1[1] + r1[2] + r1[3];
        __syncthreads();
        float act = h0 / (1.0f + __expf(-h0)) * h1 * sw[e];
        float4 w2 = *(const float4*)(experts + (size_t)2 * E_ * D_ + base + tid * 4);
        acc[0] += act * w2.x;
        acc[1] += act * w2.y;
        acc[2] += act * w2.z;
        acc[3] += act * w2.w;
    }
    size_t o = (size_t)t * D_ + tid * 4;
    float4 rv = *(const float4*)(xfi + o);
    float4 ov;
    ov.x = acc[0] + rv.x;
    ov.y = acc[1] + rv.y;
    ov.z = acc[2] + rv.z;
    ov.w = acc[3] + rv.w;
    *(float4*)(out + o) = ov;
}

// ---------------------------------------------------------------------------
extern "C" void kernel_launch(void* const* d_in, const int* in_sizes, int n_in,
                              void* d_out, int out_size, void* d_ws, size_t ws_size,
                              hipStream_t stream)
{
    (void)in_sizes; (void)n_in; (void)out_size; (void)ws_size;
    const float* x_input     = (const float*)d_in[0];
    const int*   indices     = (const int*)d_in[1];
    const float* scores      = (const float*)d_in[2];
    const float* attn_w      = (const float*)d_in[3];
    const float* attn_out_w  = (const float*)d_in[4];
    const float* attn_norm_w = (const float*)d_in[5];
    const float* ffn_norm_w  = (const float*)d_in[6];
    const float* ffn_experts = (const float*)d_in[7];
    const float* keys        = (const float*)d_in[8];
    const float* head_probs  = (const float*)d_in[9];
    const float* score_probs = (const float*)d_in[10];
    float* out = (float*)d_out;

    float* ws = (float*)d_ws;
    const size_t MF = 1024 * 1024;
    // Region map (floats), peak 12M floats = 48 MB:
    // A [0,6M): qkv (gemm1 out); after qkv_prep reused as:
    //    aob [0,1M) bf16 | xfi [1M,3M) | xf [3M,5M) | msbuf [5M,5.25M) |
    //    spbuf [5.25M,...) | woutT [5.5M,6M) bf16
    // B [6M,8M): xnb bf16 (1-3) -> qh bf16 (4-5) -> xfb bf16 (8+)
    // C [8M,10M): wqkvT bf16 (2-3) -> khb bf16 (4+)
    // D [10M,12M): vhb bf16 (4-5) -> kgath bf16 [10M,11M) (7.5+)
    float* qkv            = ws;
    unsigned short* aob   = (unsigned short*)ws;
    float* xfi            = ws + 1 * MF;
    float* xf             = ws + 3 * MF;
    float* msbuf          = ws + 5 * MF;
    float* spbuf          = ws + 5 * MF + 300 * 1024;
    unsigned short* woutT = (unsigned short*)(ws + 5 * MF + 512 * 1024);
    unsigned short* xnb   = (unsigned short*)(ws + 6 * MF);
    unsigned short* qh    = (unsigned short*)(ws + 6 * MF);
    unsigned short* xfb   = (unsigned short*)(ws + 6 * MF);
    unsigned short* wqkvT = (unsigned short*)(ws + 8 * MF);
    unsigned short* khb   = (unsigned short*)(ws + 8 * MF);
    unsigned short* vhb   = (unsigned short*)(ws + 10 * MF);
    unsigned short* kgath = (unsigned short*)(ws + 10 * MF);  // after flash

    // 1) rmsnorm -> bf16 A
    rmsnorm_bf16_kernel<<<T_, 256, 0, stream>>>(x_input, attn_norm_w, xnb);

    // 2) attn_w (1024 x 3072) -> wqkvT [3072][1024] bf16
    {
        dim3 g(3 * D_ / 32, D_ / 32);
        convt_kernel<<<g, 256, 0, stream>>>(attn_w, wqkvT, D_, 3 * D_);
    }

    // 3) qkv = xnb @ attn_w   (MFMA)
    {
        dim3 g(3 * D_ / 128, T_ / 128);
        mfma_gemm_kernel<0><<<g, 256, 0, stream>>>(xnb, wqkvT, nullptr, qkv,
                                                   T_, 3 * D_, D_);
    }

    // 4) split + l2norm + rope -> bf16 q/k/v
    qkv_prep_kernel<<<T_ * NH_, 64, 0, stream>>>(qkv, qh, khb, vhb);

    // 5) MFMA flash attention -> aob bf16
    flash_attn_mfma_kernel<<<NH_ * 16, 256, 0, stream>>>(qh, khb, vhb, aob);

    // 6) attn_out_w (1024 x 1024) -> woutT [1024][1024] bf16
    {
        dim3 g(D_ / 32, D_ / 32);
        convt_kernel<<<g, 256, 0, stream>>>(attn_out_w, woutT, D_, D_);
    }

    // 7) xfi = aob @ attn_out_w + x_input   (MFMA + residual)
    {
        dim3 g(D_ / 128, T_ / 128);
        mfma_gemm_kernel<1><<<g, 256, 0, stream>>>(aob, woutT, x_input, xfi,
                                                   T_, D_, D_);
    }

    // 7.5) gather keys columns (vhb dead after step 5)
    gather_keys_kernel<<<BC_ * ET_ * KH_, 256, 0, stream>>>(keys, indices, kgath);

    // 8) rmsnorm dual: xf fp32 + xfb bf16
    rmsnorm_dual_kernel<<<T_, 256, 0, stream>>>(xfi, ffn_norm_w, xf, xfb);

    // 9a) expert score GEMM per chunk -> msbuf
    score_gemm_kernel<<<BC_, 256, 0, stream>>>(xfb, kgath, msbuf);

    // 9b) gather sp0/sp1/hp -> spbuf
    gather_sp_kernel<<<BC_, 256, 0, stream>>>(score_probs, head_probs,
                                              indices, spbuf);

    // 10) MoE (fused combine weights) + final residual
    moe_kernel<<<T_, 256, 0, stream>>>(xf, xfi, indices, msbuf, scores, spbuf,
                                       ffn_experts, out);
}